// Round 13
// baseline (383.637 us; speedup 1.0000x reference)
//
#include <hip/hip_runtime.h>
#include <stdint.h>

namespace {

constexpr int Bn = 8;
constexpr int Sn = 2048;
constexpr int Cn = 1024;
constexpr int Mn = Bn * Sn;  // 16384

typedef float f32x4 __attribute__((ext_vector_type(4)));
typedef _Float16 f16x8 __attribute__((ext_vector_type(8)));
typedef unsigned short us8 __attribute__((ext_vector_type(8)));

__device__ __forceinline__ unsigned short f2h(float f) {
  _Float16 h = (_Float16)f;
  unsigned short u;
  __builtin_memcpy(&u, &h, 2);
  return u;
}

__device__ __forceinline__ void stage16(const unsigned short* g, unsigned short* l) {
  __builtin_amdgcn_global_load_lds(
      (const __attribute__((address_space(1))) void*)g,
      (__attribute__((address_space(3))) void*)l, 16, 0, 0);
}

// One prep kernel: x1,x2,x3 -> contiguous fp16 region; Wq,Wk,Wv -> contiguous
// fp16 region; bq|bk|bv -> bias_cat. All vectorized float4 -> ushort4.
__global__ __launch_bounds__(256) void k_prep(
    const float* __restrict__ x1, const float* __restrict__ x2,
    const float* __restrict__ x3, const float* __restrict__ Wq,
    const float* __restrict__ Wk, const float* __restrict__ Wv,
    const float* __restrict__ bq, const float* __restrict__ bk,
    const float* __restrict__ bv, unsigned short* __restrict__ xdst,
    unsigned short* __restrict__ wdst, float* __restrict__ bdst) {
  const int NX = 4194304;  // float4-packs per x array (16M elems)
  const int NW = 262144;   // float4-packs per W (1M elems)
  int tid0 = blockIdx.x * 256 + threadIdx.x;
  int stride = gridDim.x * 256;
  for (int i = tid0; i < 3 * NX + 3 * NW; i += stride) {
    const float* s;
    unsigned short* d;
    if (i < 3 * NX) {
      int a = i / NX, j = i - a * NX;
      s = (a == 0 ? x1 : a == 1 ? x2 : x3) + (size_t)j * 4;
      d = xdst + (size_t)a * 16777216 + (size_t)j * 4;
    } else {
      int k = i - 3 * NX;
      int a = k / NW, j = k - a * NW;
      s = (a == 0 ? Wq : a == 1 ? Wk : Wv) + (size_t)j * 4;
      d = wdst + (size_t)a * 1048576 + (size_t)j * 4;
    }
    float4 v = *(const float4*)s;
    ushort4 h;
    h.x = f2h(v.x); h.y = f2h(v.y); h.z = f2h(v.z); h.w = f2h(v.w);
    *(ushort4*)d = h;
  }
  if (tid0 < 768) {
    int a = tid0 >> 8, j = tid0 & 255;
    const float* s = (a == 0 ? bq : a == 1 ? bk : bv) + j * 4;
    *(float4*)(bdst + a * 1024 + j * 4) = *(const float4*)s;
  }
}

// ---------------------------------------------------------------------------
// 8-phase 256x256 plain-fp16 GEMM — unified (proven r6/r10/r11/r12 structure:
// T1 XCD-chunked decode + T2 involution swizzle [0 conflicts] + counted
// vmcnt(4) at phases 3/7 + setprio).
// MODE 0: merged Q/K/V projection, 768 blocks, virtual M=49152.
//   side 0 (y<64):    q = x1 @ Wq^T + bq -> flat fp16 O0 (d_out)
//   side 1 (64<=y<128): k = x2 @ Wk^T + bk -> fp16 O1
//   side 2 (y>=128):  vT[d][s] = (x3 @ Wv^T + bv)^T, computed with swapped
//     operand roles (A-port<-Wv rows=d, B-port<-x3 rows=s) -> direct
//     coalesced vT store into O2. Bit-identical to the old separate Vproj.
// MODE 1: QK^T per batch (batch=XCD), 512 blocks; fp32 scores (NO 1/sqrt d).
// MODE 2: PV per batch (batch=XCD), 256 blocks, K=2048; fp32 out -> Of.
// ---------------------------------------------------------------------------
template <int MODE>
__global__ __launch_bounds__(512, 2) void gemm8(
    const unsigned short* __restrict__ Ah, const unsigned short* __restrict__ Bh,
    const float* __restrict__ bias,
    unsigned short* __restrict__ O0, unsigned short* __restrict__ O1,
    unsigned short* __restrict__ O2,
    float* __restrict__ Sout, float* __restrict__ Of) {
  __shared__ unsigned short lds[65536];  // 8 regions x 16 KiB

  constexpr int KT = (MODE == 2) ? 32 : 16;  // K-tiles of 64
  constexpr int NIk = KT / 2;

  const int bid = blockIdx.x;
  const int chunk = bid & 7;   // XCD id (round-robin dispatch)
  const int r = bid >> 3;

  int tM, tN, side = 0, zdec = 0, lda, ldb;
  const unsigned short *a0, *b0;
  if constexpr (MODE == 0) {
    int y = chunk * 24 + (r >> 2);    // 0..191, XCD-contiguous x-rows
    int x = r & 3;
    side = (y >= 128) ? 2 : (y >= 64 ? 1 : 0);
    if (side < 2) {
      tM = y * 256; tN = x * 256;
      a0 = Ah; b0 = Bh + side * 1048576;
    } else {
      // swapped roles: A-port = Wv rows (d), B-port = x3 rows (s, virtual)
      tM = x * 256; tN = 32768 + (y - 128) * 256;
      a0 = Bh + 2097152; b0 = Ah;
    }
    lda = 1024; ldb = 1024;
  } else if constexpr (MODE == 1) {
    zdec = chunk;                      // batch per XCD
    int ys = r >> 5, x = (r >> 2) & 7, y4 = r & 3;
    tM = (ys * 4 + y4) * 256; tN = x * 256;
    a0 = Ah + (long long)zdec * 2097152;
    b0 = Bh + (long long)zdec * 2097152;
    lda = 1024; ldb = 1024;
  } else {
    zdec = chunk;                      // batch per XCD
    int y = r >> 2, x = r & 3;         // 8 M-tiles x 4 N-tiles
    tM = y * 256; tN = x * 256;
    a0 = Ah + (long long)zdec * 8388608;  // attn batch (16 MiB fp32-row region)
    b0 = Bh + (long long)zdec * 2048;     // vT column slice
    lda = 4096; ldb = 16384;
  }

  const int tid = threadIdx.x;
  const int l = tid & 63;
  const int w = tid >> 6;
  const int wm = w >> 2, wn = w & 3;   // 2 x 4 wave grid
  const int lr = l & 15;
  const int lk = l >> 4;
  // T2 involution: pre-swizzled global source slot + same XOR on read slot
  const int ssw = ((tid & 3) ^ ((tid >> 3) & 3)) * 8;
  const int rsw = (lk ^ ((lr >> 1) & 3)) * 8;

  // stage one 256x32 region (16 KiB): 2 x global_load_lds(16B) per thread
  auto stg = [&](int region, int tile, int ks, bool isA) {
    int tt = tile < KT ? tile : KT - 1;  // tail clamp keeps vmcnt ledger uniform
    int k0 = tt * 64 + ks * 32;
    const unsigned short* G = isA ? a0 : b0;
    const long long ld = isA ? lda : ldb;
    int tb = isA ? tM : tN;
    unsigned short* D = lds + region * 8192;
#pragma unroll
    for (int j = 0; j < 2; ++j)
      stage16(G + (long long)(tb + j * 128 + (tid >> 2)) * ld + k0 + ssw,
              D + j * 4096 + (size_t)tid * 8);
  };

  f32x4 acc[8][4] = {};

  // prologue: tile0 (both k-halves) + tile1 k-half0; regions 0,2,1,3 must land
  stg(0, 0, 0, true);  stg(2, 0, 0, false);
  stg(1, 0, 1, true);  stg(3, 0, 1, false);
  stg(4, 1, 0, true);  stg(6, 1, 0, false);
  asm volatile("s_waitcnt vmcnt(4)" ::: "memory");
  __builtin_amdgcn_sched_barrier(0);
  __builtin_amdgcn_s_barrier();

  for (int i = 0; i < NIk; ++i) {
    const int e = 2 * i;
#pragma unroll
    for (int p = 0; p < 8; ++p) {
      const int buf = p >> 2, q = p & 3, mh = q & 1, ks = q >> 1;
      const unsigned short* Ar = lds + (buf * 4 + ks) * 8192;
      const unsigned short* Br = lds + (buf * 4 + 2 + ks) * 8192;
      f16x8 av[4], bv[4];
#pragma unroll
      for (int fm = 0; fm < 4; ++fm)
        av[fm] = *(const f16x8*)&Ar[(wm * 128 + mh * 64 + fm * 16 + lr) * 32 + rsw];
#pragma unroll
      for (int fn = 0; fn < 4; ++fn)
        bv[fn] = *(const f16x8*)&Br[(wn * 64 + fn * 16 + lr) * 32 + rsw];
      // stage slots target regions whose reads completed last phase
      if (p == 0)      { stg(5, e + 1, 1, true); stg(7, e + 1, 1, false); }
      else if (p == 2) { stg(0, e + 2, 0, true); stg(2, e + 2, 0, false); }
      else if (p == 4) { stg(1, e + 2, 1, true); stg(3, e + 2, 1, false); }
      else if (p == 6) { stg(4, e + 3, 0, true); stg(6, e + 3, 0, false); }
      __builtin_amdgcn_s_barrier();
      asm volatile("s_waitcnt lgkmcnt(0)" ::: "memory");
      __builtin_amdgcn_sched_barrier(0);
      __builtin_amdgcn_s_setprio(1);
#pragma unroll
      for (int fm = 0; fm < 4; ++fm)
#pragma unroll
        for (int fn = 0; fn < 4; ++fn)
          acc[mh * 4 + fm][fn] = __builtin_amdgcn_mfma_f32_16x16x32_f16(
              av[fm], bv[fn], acc[mh * 4 + fm][fn], 0, 0, 0);
      __builtin_amdgcn_s_setprio(0);
      if (p == 3 || p == 7) {
        asm volatile("s_waitcnt vmcnt(4)" ::: "memory");
        __builtin_amdgcn_sched_barrier(0);
      }
      __builtin_amdgcn_s_barrier();
    }
  }

#pragma unroll
  for (int am = 0; am < 8; ++am)
#pragma unroll
    for (int an = 0; an < 4; ++an)
#pragma unroll
      for (int r2 = 0; r2 < 4; ++r2) {
        int rg = tM + wm * 128 + am * 16 + (l >> 4) * 4 + r2;
        int cg = tN + wn * 64 + an * 16 + lr;
        float v = acc[am][an][r2];
        if constexpr (MODE == 0) {
          if (side == 0) {
            O0[(long long)rg * 1024 + cg] = f2h(v + bias[cg]);          // q
          } else if (side == 1) {
            O1[(long long)(rg - Mn) * 1024 + cg] = f2h(v + bias[1024 + cg]);  // k
          } else {
            // vT[d=rg][s=cg-32768], coalesced along s
            O2[(long long)rg * 16384 + (cg - 32768)] = f2h(v + bias[2048 + rg]);
          }
        } else if constexpr (MODE == 1) {
          Sout[(long long)zdec * 4194304ll + (long long)rg * 2048 + cg] = v;
        } else {
          Of[(long long)zdec * 2097152ll + (long long)rg * 1024 + cg] = v;
        }
      }
}

// In-place row softmax: fp32 row [Sn] -> normalized fp16 attn in first Sn shorts.
// XCD-affine row decode: batch = blockIdx&7 matches QK^T writer / PV reader XCD.
__global__ __launch_bounds__(256) void k_softmax(float* __restrict__ S) {
  const long long row = ((long long)(blockIdx.x & 7) << 11) | (blockIdx.x >> 3);
  float* src = S + row * Sn;
  const int t = threadIdx.x;
  float4 v0 = *(const float4*)(src + t * 8);
  float4 v1 = *(const float4*)(src + t * 8 + 4);
  float m = fmaxf(fmaxf(fmaxf(v0.x, v0.y), fmaxf(v0.z, v0.w)),
                  fmaxf(fmaxf(v1.x, v1.y), fmaxf(v1.z, v1.w)));
#pragma unroll
  for (int off = 32; off > 0; off >>= 1) m = fmaxf(m, __shfl_xor(m, off));
  __shared__ float red[8];
  if ((t & 63) == 0) red[t >> 6] = m;
  __syncthreads();
  m = fmaxf(fmaxf(red[0], red[1]), fmaxf(red[2], red[3]));
  float e[8];
  e[0] = __expf(v0.x - m); e[1] = __expf(v0.y - m);
  e[2] = __expf(v0.z - m); e[3] = __expf(v0.w - m);
  e[4] = __expf(v1.x - m); e[5] = __expf(v1.y - m);
  e[6] = __expf(v1.z - m); e[7] = __expf(v1.w - m);
  float s = ((e[0] + e[1]) + (e[2] + e[3])) + ((e[4] + e[5]) + (e[6] + e[7]));
#pragma unroll
  for (int off = 32; off > 0; off >>= 1) s += __shfl_xor(s, off);
  if ((t & 63) == 0) red[4 + (t >> 6)] = s;
  __syncthreads();
  s = (red[4] + red[5]) + (red[6] + red[7]);
  float inv = 1.0f / s;
  us8 o;
#pragma unroll
  for (int j = 0; j < 8; ++j) o[j] = f2h(e[j] * inv);
  *(us8*)((unsigned short*)src + t * 8) = o;
}

}  // namespace

extern "C" void kernel_launch(void* const* d_in, const int* in_sizes, int n_in,
                              void* d_out, int out_size, void* d_ws, size_t ws_size,
                              hipStream_t stream) {
  (void)in_sizes; (void)n_in; (void)out_size;
  const float* x1 = (const float*)d_in[0];
  const float* x2 = (const float*)d_in[1];
  const float* x3 = (const float*)d_in[2];
  const float* Wq = (const float*)d_in[3];
  const float* bq = (const float*)d_in[4];
  const float* Wk = (const float*)d_in[5];
  const float* bk = (const float*)d_in[6];
  const float* Wv = (const float*)d_in[7];
  const float* bv = (const float*)d_in[8];
  float* out = (float*)d_out;
  char* ws = (char*)d_ws;

  const size_t MiB = 1048576ull;
  // ws layout (MiB): [0,6) W fp16 (Wq|Wk|Wv contiguous) [6,~6.01) bias_cat
  // [12,44) kh fp16 [44,76) vT fp16
  // [76,108) x1h [108,140) x2h [140,172) x3h  (contiguous virtual A, M=49152)
  // S fp32 [76,204) overlays x1h/x2h/x3h (dead after merged proj). NEED 204.
  unsigned short* wqk = (unsigned short*)(ws);         // Wq|Wk|Wv (1M shorts each)
  float* bias_cat = (float*)(ws + 6 * MiB);            // bq|bk|bv (3072 f32)
  unsigned short* kh  = (unsigned short*)(ws + 12 * MiB);
  unsigned short* vT  = (unsigned short*)(ws + 44 * MiB);
  unsigned short* x1h = (unsigned short*)(ws + 76 * MiB);
  float* S = (float*)(ws + 76 * MiB);
  if (ws_size < 204 * MiB) return;  // visible failure => ws probe

  unsigned short* qh = (unsigned short*)d_out;  // q flat fp16 (dead before PV)

  // 1) all casts + bias concat in one dispatch.
  k_prep<<<2048, 256, 0, stream>>>(x1, x2, x3, Wq, Wk, Wv, bq, bk, bv,
                                   x1h, wqk, bias_cat);
  // 2) merged Q/K/V projection (virtual M=49152, 768 blocks).
  gemm8<0><<<768, 512, 0, stream>>>(x1h, wqk, bias_cat, qh, kh, vT,
                                    nullptr, nullptr);
  // 3) scores = q @ k^T per batch (NO 1/sqrt(d)).
  gemm8<1><<<512, 512, 0, stream>>>(qh, kh, nullptr, nullptr, nullptr, nullptr,
                                    S, nullptr);
  // 4) in-place softmax -> fp16 attn rows (XCD-affine).
  k_softmax<<<Mn, 256, 0, stream>>>(S);
  // 5) out[b] = attn[b] @ v[b].
  gemm8<2><<<256, 512, 0, stream>>>((unsigned short*)S, vT, nullptr, nullptr,
                                    nullptr, nullptr, nullptr, out);
}

// Round 14
// 341.576 us; speedup vs baseline: 1.1231x; 1.1231x over previous
//
#include <hip/hip_runtime.h>
#include <stdint.h>

namespace {

constexpr int Bn = 8;
constexpr int Sn = 2048;
constexpr int Cn = 1024;
constexpr int Mn = Bn * Sn;  // 16384

typedef float f32x4 __attribute__((ext_vector_type(4)));
typedef _Float16 f16x8 __attribute__((ext_vector_type(8)));
typedef unsigned short us8 __attribute__((ext_vector_type(8)));

__device__ __forceinline__ unsigned short f2h(float f) {
  _Float16 h = (_Float16)f;
  unsigned short u;
  __builtin_memcpy(&u, &h, 2);
  return u;
}

__device__ __forceinline__ void stage16(const unsigned short* g, unsigned short* l) {
  __builtin_amdgcn_global_load_lds(
      (const __attribute__((address_space(1))) void*)g,
      (__attribute__((address_space(3))) void*)l, 16, 0, 0);
}

// One prep kernel: x1,x2,x3 -> contiguous fp16; Wq,Wk,Wv -> contiguous fp16;
// bq|bk|bv -> bias_cat. Vectorized float4 -> ushort4.
__global__ __launch_bounds__(256) void k_prep(
    const float* __restrict__ x1, const float* __restrict__ x2,
    const float* __restrict__ x3, const float* __restrict__ Wq,
    const float* __restrict__ Wk, const float* __restrict__ Wv,
    const float* __restrict__ bq, const float* __restrict__ bk,
    const float* __restrict__ bv, unsigned short* __restrict__ xdst,
    unsigned short* __restrict__ wdst, float* __restrict__ bdst) {
  const int NX = 4194304;  // float4-packs per x array (16M elems)
  const int NW = 262144;   // float4-packs per W (1M elems)
  int tid0 = blockIdx.x * 256 + threadIdx.x;
  int stride = gridDim.x * 256;
  for (int i = tid0; i < 3 * NX + 3 * NW; i += stride) {
    const float* s;
    unsigned short* d;
    if (i < 3 * NX) {
      int a = i / NX, j = i - a * NX;
      s = (a == 0 ? x1 : a == 1 ? x2 : x3) + (size_t)j * 4;
      d = xdst + (size_t)a * 16777216 + (size_t)j * 4;
    } else {
      int k = i - 3 * NX;
      int a = k / NW, j = k - a * NW;
      s = (a == 0 ? Wq : a == 1 ? Wk : Wv) + (size_t)j * 4;
      d = wdst + (size_t)a * 1048576 + (size_t)j * 4;
    }
    float4 v = *(const float4*)s;
    ushort4 h;
    h.x = f2h(v.x); h.y = f2h(v.y); h.z = f2h(v.z); h.w = f2h(v.w);
    *(ushort4*)d = h;
  }
  if (tid0 < 768) {
    int a = tid0 >> 8, j = tid0 & 255;
    const float* s = (a == 0 ? bq : a == 1 ? bk : bv) + j * 4;
    *(float4*)(bdst + a * 1024 + j * 4) = *(const float4*)s;
  }
}

// ---------------------------------------------------------------------------
// 8-phase 256x256 plain-fp16 GEMM — unified (r12-proven structure: T1
// XCD-chunked decode + T2 involution swizzle [0 conflicts] + counted
// vmcnt(4) at phases 3/7 + setprio).
// MODE 0: merged QK-projection, 512 blocks. Virtual M=32768; side=tM>=Mn
//         selects Wk. q rows -> flat fp16 O0 (d_out); k rows -> fp16 O1.
// MODE 1: QK^T per batch (batch=XCD), 512 blocks; fp32 scores (NO 1/sqrt d).
// MODE 2: PV per batch (batch=XCD), 256 blocks, K=2048; fp32 out -> Of.
// MODE 3: Vproj, 256 blocks, N-chunked per XCD. A=Wv, B=x3h, row bias,
//         fp16 out vT (ldc 16384).
// ---------------------------------------------------------------------------
template <int MODE>
__global__ __launch_bounds__(512, 2) void gemm8(
    const unsigned short* __restrict__ Ah, const unsigned short* __restrict__ Bh,
    const float* __restrict__ bias,
    unsigned short* __restrict__ O0, unsigned short* __restrict__ O1,
    float* __restrict__ Sout, float* __restrict__ Of) {
  __shared__ unsigned short lds[65536];  // 8 regions x 16 KiB

  constexpr int KT = (MODE == 2) ? 32 : 16;  // K-tiles of 64
  constexpr int NIk = KT / 2;

  const int bid = blockIdx.x;
  const int chunk = bid & 7;   // XCD id (round-robin dispatch)
  const int r = bid >> 3;

  int tM, tN, side = 0, zdec = 0, lda, ldb;
  const unsigned short *a0, *b0;
  if constexpr (MODE == 0) {
    int y = chunk * 16 + (r >> 2);    // XCD-contiguous rows: A ~1x fetch
    int x = r & 3;
    tM = y * 256; tN = x * 256;
    side = (y >= 64);
    a0 = Ah; b0 = Bh + side * 1048576;
    lda = 1024; ldb = 1024;
  } else if constexpr (MODE == 1) {
    zdec = chunk;                      // batch per XCD
    int ys = r >> 5, x = (r >> 2) & 7, y4 = r & 3;
    tM = (ys * 4 + y4) * 256; tN = x * 256;
    a0 = Ah + (long long)zdec * 2097152;
    b0 = Bh + (long long)zdec * 2097152;
    lda = 1024; ldb = 1024;
  } else if constexpr (MODE == 2) {
    zdec = chunk;                      // batch per XCD
    int y = r >> 2, x = r & 3;         // 8 M-tiles x 4 N-tiles
    tM = y * 256; tN = x * 256;
    a0 = Ah + (long long)zdec * 8388608;  // attn batch (16 MiB fp32-row region)
    b0 = Bh + (long long)zdec * 2048;     // vT column slice
    lda = 4096; ldb = 16384;
  } else {
    int x = chunk * 8 + (r >> 2);      // XCD-contiguous B cols (x3 panels)
    int y = r & 3;
    tN = x * 256; tM = y * 256;
    a0 = Ah; b0 = Bh;
    lda = 1024; ldb = 1024;
  }

  const int tid = threadIdx.x;
  const int l = tid & 63;
  const int w = tid >> 6;
  const int wm = w >> 2, wn = w & 3;   // 2 x 4 wave grid
  const int lr = l & 15;
  const int lk = l >> 4;
  // T2 involution: pre-swizzled global source slot + same XOR on read slot
  const int ssw = ((tid & 3) ^ ((tid >> 3) & 3)) * 8;
  const int rsw = (lk ^ ((lr >> 1) & 3)) * 8;

  // stage one 256x32 region (16 KiB): 2 x global_load_lds(16B) per thread
  auto stg = [&](int region, int tile, int ks, bool isA) {
    int tt = tile < KT ? tile : KT - 1;  // tail clamp keeps vmcnt ledger uniform
    int k0 = tt * 64 + ks * 32;
    const unsigned short* G = isA ? a0 : b0;
    const long long ld = isA ? lda : ldb;
    int tb = isA ? tM : tN;
    unsigned short* D = lds + region * 8192;
#pragma unroll
    for (int j = 0; j < 2; ++j)
      stage16(G + (long long)(tb + j * 128 + (tid >> 2)) * ld + k0 + ssw,
              D + j * 4096 + (size_t)tid * 8);
  };

  f32x4 acc[8][4] = {};

  // prologue: tile0 (both k-halves) + tile1 k-half0; regions 0,2,1,3 must land
  stg(0, 0, 0, true);  stg(2, 0, 0, false);
  stg(1, 0, 1, true);  stg(3, 0, 1, false);
  stg(4, 1, 0, true);  stg(6, 1, 0, false);
  asm volatile("s_waitcnt vmcnt(4)" ::: "memory");
  __builtin_amdgcn_sched_barrier(0);
  __builtin_amdgcn_s_barrier();

  for (int i = 0; i < NIk; ++i) {
    const int e = 2 * i;
#pragma unroll
    for (int p = 0; p < 8; ++p) {
      const int buf = p >> 2, q = p & 3, mh = q & 1, ks = q >> 1;
      const unsigned short* Ar = lds + (buf * 4 + ks) * 8192;
      const unsigned short* Br = lds + (buf * 4 + 2 + ks) * 8192;
      f16x8 av[4], bv[4];
#pragma unroll
      for (int fm = 0; fm < 4; ++fm)
        av[fm] = *(const f16x8*)&Ar[(wm * 128 + mh * 64 + fm * 16 + lr) * 32 + rsw];
#pragma unroll
      for (int fn = 0; fn < 4; ++fn)
        bv[fn] = *(const f16x8*)&Br[(wn * 64 + fn * 16 + lr) * 32 + rsw];
      // stage slots target regions whose reads completed last phase
      if (p == 0)      { stg(5, e + 1, 1, true); stg(7, e + 1, 1, false); }
      else if (p == 2) { stg(0, e + 2, 0, true); stg(2, e + 2, 0, false); }
      else if (p == 4) { stg(1, e + 2, 1, true); stg(3, e + 2, 1, false); }
      else if (p == 6) { stg(4, e + 3, 0, true); stg(6, e + 3, 0, false); }
      __builtin_amdgcn_s_barrier();
      asm volatile("s_waitcnt lgkmcnt(0)" ::: "memory");
      __builtin_amdgcn_sched_barrier(0);
      __builtin_amdgcn_s_setprio(1);
#pragma unroll
      for (int fm = 0; fm < 4; ++fm)
#pragma unroll
        for (int fn = 0; fn < 4; ++fn)
          acc[mh * 4 + fm][fn] = __builtin_amdgcn_mfma_f32_16x16x32_f16(
              av[fm], bv[fn], acc[mh * 4 + fm][fn], 0, 0, 0);
      __builtin_amdgcn_s_setprio(0);
      if (p == 3 || p == 7) {
        asm volatile("s_waitcnt vmcnt(4)" ::: "memory");
        __builtin_amdgcn_sched_barrier(0);
      }
      __builtin_amdgcn_s_barrier();
    }
  }

#pragma unroll
  for (int am = 0; am < 8; ++am)
#pragma unroll
    for (int an = 0; an < 4; ++an)
#pragma unroll
      for (int r2 = 0; r2 < 4; ++r2) {
        int rg = tM + wm * 128 + am * 16 + (l >> 4) * 4 + r2;
        int cg = tN + wn * 64 + an * 16 + lr;
        float v = acc[am][an][r2];
        if constexpr (MODE == 0) {
          if (!side) {
            O0[(long long)rg * 1024 + cg] = f2h(v + bias[cg]);              // q
          } else {
            O1[(long long)(rg - Mn) * 1024 + cg] = f2h(v + bias[1024 + cg]);  // k
          }
        } else if constexpr (MODE == 1) {
          Sout[(long long)zdec * 4194304ll + (long long)rg * 2048 + cg] = v;
        } else if constexpr (MODE == 2) {
          Of[(long long)zdec * 2097152ll + (long long)rg * 1024 + cg] = v;
        } else {
          O0[(long long)rg * 16384 + cg] = f2h(v + bias[2048 + rg]);  // vT fp16
        }
      }
}

// In-place row softmax: fp32 row [Sn] -> normalized fp16 attn in first Sn shorts.
// XCD-affine row decode: batch = blockIdx&7 matches QK^T writer / PV reader XCD.
__global__ __launch_bounds__(256) void k_softmax(float* __restrict__ S) {
  const long long row = ((long long)(blockIdx.x & 7) << 11) | (blockIdx.x >> 3);
  float* src = S + row * Sn;
  const int t = threadIdx.x;
  float4 v0 = *(const float4*)(src + t * 8);
  float4 v1 = *(const float4*)(src + t * 8 + 4);
  float m = fmaxf(fmaxf(fmaxf(v0.x, v0.y), fmaxf(v0.z, v0.w)),
                  fmaxf(fmaxf(v1.x, v1.y), fmaxf(v1.z, v1.w)));
#pragma unroll
  for (int off = 32; off > 0; off >>= 1) m = fmaxf(m, __shfl_xor(m, off));
  __shared__ float red[8];
  if ((t & 63) == 0) red[t >> 6] = m;
  __syncthreads();
  m = fmaxf(fmaxf(red[0], red[1]), fmaxf(red[2], red[3]));
  float e[8];
  e[0] = __expf(v0.x - m); e[1] = __expf(v0.y - m);
  e[2] = __expf(v0.z - m); e[3] = __expf(v0.w - m);
  e[4] = __expf(v1.x - m); e[5] = __expf(v1.y - m);
  e[6] = __expf(v1.z - m); e[7] = __expf(v1.w - m);
  float s = ((e[0] + e[1]) + (e[2] + e[3])) + ((e[4] + e[5]) + (e[6] + e[7]));
#pragma unroll
  for (int off = 32; off > 0; off >>= 1) s += __shfl_xor(s, off);
  if ((t & 63) == 0) red[4 + (t >> 6)] = s;
  __syncthreads();
  s = (red[4] + red[5]) + (red[6] + red[7]);
  float inv = 1.0f / s;
  us8 o;
#pragma unroll
  for (int j = 0; j < 8; ++j) o[j] = f2h(e[j] * inv);
  *(us8*)((unsigned short*)src + t * 8) = o;
}

}  // namespace

extern "C" void kernel_launch(void* const* d_in, const int* in_sizes, int n_in,
                              void* d_out, int out_size, void* d_ws, size_t ws_size,
                              hipStream_t stream) {
  (void)in_sizes; (void)n_in; (void)out_size;
  const float* x1 = (const float*)d_in[0];
  const float* x2 = (const float*)d_in[1];
  const float* x3 = (const float*)d_in[2];
  const float* Wq = (const float*)d_in[3];
  const float* Wk = (const float*)d_in[5];
  const float* Wv = (const float*)d_in[7];
  const float* bq = (const float*)d_in[4];
  const float* bk = (const float*)d_in[6];
  const float* bv = (const float*)d_in[8];
  float* out = (float*)d_out;
  char* ws = (char*)d_ws;

  const size_t MiB = 1048576ull;
  // ws layout (MiB): [0,6) W fp16 (Wq|Wk|Wv contiguous) [6,~6.01) bias_cat
  // [12,44) kh fp16 [44,76) vT fp16
  // [76,108) x1h [108,140) x2h [140,172) x3h (contiguous fp16 x region)
  // S fp32 [76,204) overlays x1h/x2h/x3h (dead after projections). NEED 204.
  unsigned short* wqk = (unsigned short*)(ws);         // Wq|Wk|Wv (1M shorts each)
  float* bias_cat = (float*)(ws + 6 * MiB);            // bq|bk|bv (3072 f32)
  unsigned short* kh  = (unsigned short*)(ws + 12 * MiB);
  unsigned short* vT  = (unsigned short*)(ws + 44 * MiB);
  unsigned short* x1h = (unsigned short*)(ws + 76 * MiB);
  unsigned short* x3h = (unsigned short*)(ws + 140 * MiB);
  float* S = (float*)(ws + 76 * MiB);
  if (ws_size < 204 * MiB) return;  // visible failure => ws probe

  unsigned short* qh = (unsigned short*)d_out;  // q flat fp16 (dead before PV)

  // 1) all casts + bias concat in one dispatch.
  k_prep<<<2048, 256, 0, stream>>>(x1, x2, x3, Wq, Wk, Wv, bq, bk, bv,
                                   x1h, wqk, bias_cat);
  // 2) Vproj (256 blocks): vT = (x3 @ Wv^T + bv)^T directly.
  gemm8<3><<<256, 512, 0, stream>>>(wqk + 2097152, x3h, bias_cat, vT, nullptr,
                                    nullptr, nullptr);
  // 3) merged Q+K projection (virtual M=32768, 512 blocks).
  gemm8<0><<<512, 512, 0, stream>>>(x1h, wqk, bias_cat, qh, kh, nullptr, nullptr);
  // 4) scores = q @ k^T per batch (NO 1/sqrt(d)).
  gemm8<1><<<512, 512, 0, stream>>>(qh, kh, nullptr, nullptr, nullptr, S, nullptr);
  // 5) in-place softmax -> fp16 attn rows (XCD-affine).
  k_softmax<<<Mn, 256, 0, stream>>>(S);
  // 6) out[b] = attn[b] @ v[b].
  gemm8<2><<<256, 512, 0, stream>>>((unsigned short*)S, vT, nullptr, nullptr,
                                    nullptr, nullptr, out);
}